// Round 5
// baseline (191.201 us; speedup 1.0000x reference)
//
#include <hip/hip_runtime.h>

// EquiConv fused MFMA kernel for MI355X (gfx950) — round 10.
// Evidence through R9: wait granularity (R7->R9) and prefetch depth (R8) have
// ZERO effect; waves/CU scales time linearly (R8: 8->4 waves = 2.1x). The
// kernel is TLP-starved: ~54% dual-wave stall, occupancy capped at 2 waves/SIMD
// by LDS (72KB) and regs (80 VGPR f32 hoist + 96 acc). R10 attacks occupancy:
//  - ring 5->3 slots (3KB each, 9KB/wave, depth-2-half; depth proven irrelevant)
//    -> LDS pool 47.4KB -> 3 blocks/CU; 625 blocks <= 768 slots = 1 round.
//  - launch_bounds(256,3) -> 12 waves/CU.
//  - hoist arrays (xe/xo/y0/y1/y2) packed as bf16 pairs: 80->40 VGPRs; unpack
//    is 1 shl/and per element (fills idle issue slots). One extra bf16 rounding
//    on x2 (A-operand is bf16 anyway).
//  - sched_barrier(0) -> sched_barrier(0xF): VALU/MFMA may cross wait points
//    (compiler can pipeline across chunks); VMEM/DS stay pinned (correctness).
// prep_weights unchanged from R7 (dest-linear gather).

#define E_TOT 20000

typedef __attribute__((ext_vector_type(8))) short short8;
typedef __attribute__((ext_vector_type(4))) float f32x4;
typedef __attribute__((ext_vector_type(2))) __bf16 bf16x2;

#define FRAG_USH 512
#define HALF_USH 1536          // 3 frags = 3KB (ring slot)
#define CH_USH   3072          // 6 frags = 6KB (stream layout unit)
#define N_CH     52
#define NSLOT    3             // ring slots per wave (3 x 3KB = 9KB/wave)
#define STRIDE_W 159744        // 312 frags * 512 ushort per wave stream
#define FC1_OFF  638976        // 4*STRIDE_W
#define FC2_OFF  647168
#define FC3_OFF  651264
#define WS_USH   657408        // 1.28 MB of d_ws

// LDS pool carve (bytes): ring 36864 + x1s 4224 + x1v 6272 = 47360 (3 blk/CU)
#define X1S_OFF  36864
#define X1V_OFF  41088
#define POOL_B   47360

__device__ __forceinline__ unsigned short f2b(float f){
  return __builtin_bit_cast(unsigned short, (__bf16)f);
}
__device__ __forceinline__ unsigned f2b2(float lo, float hi){
  bf16x2 t; t[0] = (__bf16)lo; t[1] = (__bf16)hi;
  return __builtin_bit_cast(unsigned, t);
}
__device__ __forceinline__ float b2f(unsigned short h){
  return __uint_as_float(((unsigned)h) << 16);
}
__device__ __forceinline__ float ulo(unsigned u){ return __uint_as_float(u << 16); }
__device__ __forceinline__ float uhi(unsigned u){ return __uint_as_float(u & 0xFFFF0000u); }
__device__ __forceinline__ f32x4 mfma16(short8 a, short8 b, f32x4 c){
  return __builtin_amdgcn_mfma_f32_16x16x32_bf16(a, b, c, 0, 0, 0);
}
union U8 { short8 v; unsigned u[4]; };
__device__ __forceinline__ float silu_f(float x){ return x/(1.f+__expf(-x)); }
__device__ __forceinline__ float sigm_f(float x){ return 1.f/(1.f+__expf(-x)); }

// PACK8P: a = bf16(s * unpack(xp[0..3])), pair order (lo,hi) == old (x[2q],x[2q+1])
#define PACK8P(a, s, xp) { \
  a.u[0]=f2b2((s)*ulo((xp)[0]),(s)*uhi((xp)[0])); \
  a.u[1]=f2b2((s)*ulo((xp)[1]),(s)*uhi((xp)[1])); \
  a.u[2]=f2b2((s)*ulo((xp)[2]),(s)*uhi((xp)[2])); \
  a.u[3]=f2b2((s)*ulo((xp)[3]),(s)*uhi((xp)[3])); }

// s_waitcnt simm16: vmcnt[3:0]|[15:14], expcnt[6:4], lgkmcnt[11:8]
// vmcnt(6)=0x0F76 vmcnt(3)=0x0F73 vmcnt(0)=0x0F70 ; lgkm(0),vm-nowait=0xC07F
// sched_barrier mask 0xF = ALU|VALU|SALU|MFMA may cross; VMEM/DS pinned.
#define WVC(code) { __builtin_amdgcn_s_waitcnt(code); __builtin_amdgcn_sched_barrier(0xF); }
#define GUARD     { __builtin_amdgcn_s_waitcnt(0xC07F); __builtin_amdgcn_sched_barrier(0xF); }

// dest position of (k_local, n16) inside a 512-ushort fragment
__device__ __forceinline__ int fpos(int kl, int n16){
  return (kl>>3)*128 + n16*8 + (kl&7);
}

// ---------------- prep: dest-linear gather into per-wave streams ----------------
__global__ void prep_weights(const float* __restrict__ ss_s, const float* __restrict__ ss_g,
                             const float* __restrict__ vv_s, const float* __restrict__ vv_g,
                             const float* __restrict__ sv,   const float* __restrict__ vs,
                             const float* __restrict__ w1,   const float* __restrict__ w2,
                             const float* __restrict__ w3,   unsigned short* __restrict__ wsb)
{
  int g = blockIdx.x * 256 + threadIdx.x;
  if (g >= WS_USH/8) return;
  const int dest = g << 3;
  const float A_SC  = 0.013975424859373686f;                     // 1/sqrt(S*S+V*V)
  const float A_VV  = (float)(0.013975424859373686 * 0.5773502691896258);
  const float A_VEC = 0.015625f;                                 // 1/sqrt(2*S*V)

  const float* src = nullptr;
  int stride = 0;
  float scale = 1.f;

  if (dest < FC1_OFF) {                      // 4 per-wave streams
    int wave = dest / STRIDE_W;
    int off  = dest - wave*STRIDE_W;
    int c    = off / CH_USH;
    int rem  = off - c*CH_USH;
    int t    = rem >> 9;                     // fragment 0..5
    int p    = rem & 511;
    int kl   = (p >> 7) << 3;                // base kl; +j inside group
    int n16  = (p >> 3) & 15;
    if (c < 32) {                            // SS: ss_s (t0..3) + ss_g (t4,5)
      int u = (wave<<4) + (c>>1);
      int v = ((c&1)<<5) + kl;
      if (t < 4) { src = ss_s + (u<<12)+(v<<6)+((t<<4)+n16);     stride = 64; }
      else       { src = ss_g + (u<<11)+(v<<5)+(((t-4)<<4)+n16); stride = 32; }
      scale = A_SC;
    } else if (c < 40) {                     // VV: vv_s (t0..3) + vv_g (t4,5)
      int u = (wave<<3) + (c-32);
      int v = kl;
      if (t < 4) { src = vv_s + (u<<11)+(v<<6)+((t<<4)+n16);     stride = 64; }
      else       { src = vv_g + (u<<10)+(v<<5)+(((t-4)<<4)+n16); stride = 32; }
      scale = A_VV;
    } else if (c < 46) {                     // SV: chunks 40..45, ul = ch*3 + t/2
      int ul = (c-40)*3 + (t>>1);
      if (ul < 16) {
        int u = (wave<<4) + ul;
        src = sv + (u<<10)+(kl<<5)+(((t&1)<<4)+n16);
        stride = 32; scale = A_VEC;
      }                                      // else: gap frag (c=45,t>=2) -> 0
    } else {                                 // VS: chunks 46..51
      int cc = c - 46;
      int vh = cc/3, ch3 = cc - vh*3;
      int fseq = ch3*6 + t;
      if (fseq < 16) {
        int u = (wave<<3) + (fseq>>1);
        int v = (vh<<5) + kl;
        src = vs + (u<<11)+(v<<5)+(((fseq&1)<<4)+n16);
        stride = 32; scale = A_VEC;
      }                                      // else: gap frag (ch3=2,t>=4) -> 0
    }
  } else if (dest < FC2_OFF) {               // fc1 [128][64]
    int off = dest - FC1_OFF;
    int fi = off >> 9, p = off & 511;
    int kl = (p>>7)<<3, n16 = (p>>3)&15;
    int k = ((fi>>2)<<5) + kl, n = ((fi&3)<<4) + n16;
    src = w1 + (k<<6) + n; stride = 64;
  } else if (dest < FC3_OFF) {               // fc2 [64][64]
    int off = dest - FC2_OFF;
    int fi = off >> 9, p = off & 511;
    int kl = (p>>7)<<3, n16 = (p>>3)&15;
    int k = ((fi>>2)<<5) + kl, n = ((fi&3)<<4) + n16;
    src = w2 + (k<<6) + n; stride = 64;
  } else {                                   // fc3 [64][96]
    int off = dest - FC3_OFF;
    int fi = off >> 9, p = off & 511;
    int kl = (p>>7)<<3, n16 = (p>>3)&15;
    int koff = fi/6, nhi = fi - koff*6;
    int k = (koff<<5) + kl, n = (nhi<<4) + n16;
    src = w3 + k*96 + n; stride = 96;
  }

  U8 a;
  if (src) {
    float v0 = scale * src[0*stride], v1 = scale * src[1*stride];
    float v2 = scale * src[2*stride], v3 = scale * src[3*stride];
    float v4 = scale * src[4*stride], v5 = scale * src[5*stride];
    float v6 = scale * src[6*stride], v7 = scale * src[7*stride];
    a.u[0] = f2b2(v0, v1); a.u[1] = f2b2(v2, v3);
    a.u[2] = f2b2(v4, v5); a.u[3] = f2b2(v6, v7);
  } else {
    a.u[0] = 0; a.u[1] = 0; a.u[2] = 0; a.u[3] = 0;
  }
  *(short8*)(wsb + dest) = a.v;
}

// ---------------- main fused kernel ----------------
__global__ __launch_bounds__(256, 3)
void equiconv_main(const float* __restrict__ fea1,
                   const float* __restrict__ fea2,
                   const float* __restrict__ few,
                   const float* __restrict__ fb1,
                   const float* __restrict__ fb2,
                   const float* __restrict__ fb3,
                   const unsigned short* __restrict__ wsb,
                   float* __restrict__ out)
{
  __shared__ __align__(16) unsigned char pool[POOL_B];
  unsigned short* ring = (unsigned short*)pool;                 // 36864B ring
  unsigned short* x1s_ = (unsigned short*)(pool + X1S_OFF);     // 32*66*2
  unsigned short* x1v_ = (unsigned short*)(pool + X1V_OFF);     // 32*98*2
  unsigned short* hb_  = (unsigned short*)(pool + X1S_OFF);     // alias x1 (dead post-K)
  float*          redf = (float*)pool;                          // alias ring (dead post-K)

  #define X1S(r, cc) x1s_[(r)*66 + (cc)]
  #define X1V(r, cc) x1v_[(r)*98 + (cc)]
  #define HB(w, r, cc) hb_[(((w)<<4) + (r))*72 + (cc)]

  const int tid  = threadIdx.x;
  const int lane = tid & 63, wv = tid >> 6;
  const int ln   = lane & 15, quad = lane >> 4, q8 = quad << 3;
  const int ebase = blockIdx.x << 5;          // 625 * 32 == 20000 exactly

  // ---- stage x1 (32 edges) into LDS as bf16 ----
  for (int it = tid; it < 1280; it += 256){
    int row = it / 40, seg = it - row*40;
    float4 v1 = *(const float4*)(fea1 + (size_t)(ebase + row)*160 + seg*4);
    const float* p1 = (const float*)&v1;
    int c0 = seg*4;
    #pragma unroll
    for (int jj = 0; jj < 4; jj++){
      int col = c0 + jj;
      if (col < 64) X1S(row, col) = f2b(p1[jj]);
      else          X1V(row, col-64) = f2b(p1[jj]);
    }
  }
  __syncthreads();

  // ---- hoist per-lane x2 fragments, packed as bf16 pairs (40 VGPRs) ----
  unsigned xep[2][4], xop[2][4], y0p[2][4], y1p[2][4], y2p[2][4];
  #pragma unroll
  for (int s = 0; s < 2; s++){
    const float* p = fea2 + (size_t)(ebase + s*16 + ln)*160;
    float4 a0 = *(const float4*)(p + q8);
    float4 a1 = *(const float4*)(p + q8 + 4);
    float4 b0 = *(const float4*)(p + 32 + q8);
    float4 b1 = *(const float4*)(p + 36 + q8);
    xep[s][0]=f2b2(a0.x,a0.y); xep[s][1]=f2b2(a0.z,a0.w);
    xep[s][2]=f2b2(a1.x,a1.y); xep[s][3]=f2b2(a1.z,a1.w);
    xop[s][0]=f2b2(b0.x,b0.y); xop[s][1]=f2b2(b0.z,b0.w);
    xop[s][2]=f2b2(b1.x,b1.y); xop[s][3]=f2b2(b1.z,b1.w);
    const float* py = p + 64 + q8*3;
    float yb[24];
    #pragma unroll
    for (int t = 0; t < 12; t++){
      float2 f2v = *(const float2*)(py + 2*t);
      yb[2*t] = f2v.x; yb[2*t+1] = f2v.y;
    }
    #pragma unroll
    for (int q = 0; q < 4; q++){
      y0p[s][q] = f2b2(yb[6*q+0], yb[6*q+3]);
      y1p[s][q] = f2b2(yb[6*q+1], yb[6*q+4]);
      y2p[s][q] = f2b2(yb[6*q+2], yb[6*q+5]);
    }
  }

  // ---- wave-private ring: 3 slots x 3KB, 2 halves (6KB) in flight ----
  const unsigned short* gstream = wsb + (size_t)wv*STRIDE_W;
  const int rbase = wv*NSLOT*HALF_USH;        // ushort offset of this wave's slots
  auto issue_half = [&](int h){
    const unsigned short* g = gstream + h*HALF_USH + lane*8;
    unsigned short* l = &ring[rbase + (h%NSLOT)*HALF_USH];
    #pragma unroll
    for (int q = 0; q < 3; q++)
      __builtin_amdgcn_global_load_lds(
        (const __attribute__((address_space(1))) unsigned int*)(g + q*FRAG_USH),
        (__attribute__((address_space(3))) unsigned int*)(l + q*FRAG_USH),
        16, 0, 0);
  };
  issue_half(0); issue_half(1); issue_half(2);   // prime: 9 loads

  const int r0 = ln, r1 = 16 + ln;            // x1 rows for sub0/sub1
  const f32x4 z4 = {0.f,0.f,0.f,0.f};
  f32x4 accS[2][6] = {{z4,z4,z4,z4,z4,z4},{z4,z4,z4,z4,z4,z4}};
  f32x4 accV[2][3][2] = {{{z4,z4},{z4,z4},{z4,z4}},{{z4,z4},{z4,z4},{z4,z4}}};

  // Per half: wait vmcnt(6) (half h arrived; h+1,h+2 in flight), 3 ds_reads,
  // lgkm(0) guard (reads retired), issue h+3 (overwrites just-read slot h%3).
  #define READCH(cc, bb, WA, IA, WB, IB) { \
    const int h0_ = 2*(cc); \
    WVC(WA); \
    { const unsigned short* pA_ = &ring[rbase + (h0_%NSLOT)*HALF_USH + lane*8]; \
      bb[0] = *(const short8*)(pA_); \
      bb[1] = *(const short8*)(pA_ + FRAG_USH); \
      bb[2] = *(const short8*)(pA_ + 2*FRAG_USH); } \
    if (IA) { GUARD; issue_half(h0_ + 3); } \
    WVC(WB); \
    { const unsigned short* pB_ = &ring[rbase + ((h0_+1)%NSLOT)*HALF_USH + lane*8]; \
      bb[3] = *(const short8*)(pB_); \
      bb[4] = *(const short8*)(pB_ + FRAG_USH); \
      bb[5] = *(const short8*)(pB_ + 2*FRAG_USH); } \
    if (IB) { GUARD; issue_half(h0_ + 4); } }

  // ===== SS: chunks 0..31; c = 2*u16 + half =====
  #pragma unroll 2
  for (int c = 0; c < 32; c++){
    int u = (wv<<4) + (c>>1);
    float s0 = b2f(X1S(r0, u));
    float s1 = b2f(X1S(r1, u));
    U8 a0, a1;
    if (c & 1){ PACK8P(a0, s0, xop[0]); PACK8P(a1, s1, xop[1]); }
    else      { PACK8P(a0, s0, xep[0]); PACK8P(a1, s1, xep[1]); }
    short8 bb[6];
    READCH(c, bb, 0x0F76, 1, 0x0F76, 1);
    #pragma unroll
    for (int t = 0; t < 6; t++){
      accS[0][t] = mfma16(a0.v, bb[t], accS[0][t]);
      accS[1][t] = mfma16(a1.v, bb[t], accS[1][t]);
    }
  }
  // ===== VV: chunks 32..39; one u per chunk =====
  #pragma unroll 1
  for (int k8 = 0; k8 < 8; k8++){
    int c = 32 + k8, u = (wv<<3) + k8;
    U8 a[2];
    #pragma unroll
    for (int s = 0; s < 2; s++){
      int rr = s ? r1 : r0;
      float c0 = b2f(X1V(rr, u*3+0));
      float c1 = b2f(X1V(rr, u*3+1));
      float c2 = b2f(X1V(rr, u*3+2));
      #pragma unroll
      for (int q = 0; q < 4; q++){
        float lo = c0*ulo(y0p[s][q]) + c1*ulo(y1p[s][q]) + c2*ulo(y2p[s][q]);
        float hi = c0*uhi(y0p[s][q]) + c1*uhi(y1p[s][q]) + c2*uhi(y2p[s][q]);
        a[s].u[q] = f2b2(lo, hi);
      }
    }
    short8 bb[6];
    READCH(c, bb, 0x0F76, 1, 0x0F76, 1);
    #pragma unroll
    for (int t = 0; t < 6; t++){
      accS[0][t] = mfma16(a[0].v, bb[t], accS[0][t]);
      accS[1][t] = mfma16(a[1].v, bb[t], accS[1][t]);
    }
  }
  // ===== SV: chunks 40..45; 3 u per chunk, 2 frags each =====
  #pragma unroll 1
  for (int ch = 0; ch < 6; ch++){
    int c = 40 + ch;
    short8 bb[6];
    READCH(c, bb, 0x0F76, 1, 0x0F76, 1);
    #pragma unroll
    for (int uu = 0; uu < 3; uu++){
      int ui = ch*3 + uu;
      if (ui < 16){
        int u = (wv<<4) + ui;
        float s0 = b2f(X1S(r0, u));
        float s1 = b2f(X1S(r1, u));
        U8 a[2][3];
        PACK8P(a[0][0], s0, y0p[0]); PACK8P(a[0][1], s0, y1p[0]); PACK8P(a[0][2], s0, y2p[0]);
        PACK8P(a[1][0], s1, y0p[1]); PACK8P(a[1][1], s1, y1p[1]); PACK8P(a[1][2], s1, y2p[1]);
        #pragma unroll
        for (int t = 0; t < 2; t++){
          short8 b8 = bb[uu*2 + t];
          #pragma unroll
          for (int s = 0; s < 2; s++)
            #pragma unroll
            for (int i = 0; i < 3; i++)
              accV[s][i][t] = mfma16(a[s][i].v, b8, accV[s][i][t]);
        }
      }
    }
  }
  // ===== VS: chunks 46..51; phase p (xe/xo), 3 u per chunk, 2 frags each =====
  #define VSBODY(pcv, bb) { \
    const int p_ = (pcv)/3, ch_ = (pcv) - p_*3; \
    _Pragma("unroll") \
    for (int uu = 0; uu < 3; uu++){ \
      int ui = ch_*3 + uu; \
      if (ui < 8){ \
        int u = (wv<<3) + ui; \
        U8 a[2][3]; \
        _Pragma("unroll") \
        for (int s = 0; s < 2; s++){ \
          int rr = s ? r1 : r0; \
          float c0 = b2f(X1V(rr, u*3+0)); \
          float c1 = b2f(X1V(rr, u*3+1)); \
          float c2 = b2f(X1V(rr, u*3+2)); \
          const unsigned* xx = p_ ? xop[s] : xep[s]; \
          PACK8P(a[s][0], c0, xx); PACK8P(a[s][1], c1, xx); PACK8P(a[s][2], c2, xx); \
        } \
        _Pragma("unroll") \
        for (int t = 0; t < 2; t++){ \
          short8 b8 = bb[uu*2 + t]; \
          _Pragma("unroll") \
          for (int s = 0; s < 2; s++) \
            _Pragma("unroll") \
            for (int i = 0; i < 3; i++) \
              accV[s][i][t] = mfma16(a[s][i].v, b8, accV[s][i][t]); \
        } \
      } \
    } }

  #pragma unroll 1
  for (int pc = 0; pc < 4; pc++){            // chunks 46..49: normal issue
    short8 bb[6];
    READCH(46+pc, bb, 0x0F76, 1, 0x0F76, 1);
    VSBODY(pc, bb);
  }
  {                                          // chunk 50: issue 103 (last), then stop
    short8 bb[6];
    READCH(50, bb, 0x0F76, 1, 0x0F76, 0);
    VSBODY(4, bb);
  }
  {                                          // chunk 51: drain 6 -> 3 -> 0
    short8 bb[6];
    READCH(51, bb, 0x0F73, 0, 0x0F70, 0);
    VSBODY(5, bb);
  }

  // ---- gather partials: T0 = sub0's 12 tiles, T1 = sub1's ----
  f32x4 T0[12], T1[12];
  #pragma unroll
  for (int t = 0; t < 6; t++){ T0[t] = accS[0][t]; T1[t] = accS[1][t]; }
  #pragma unroll
  for (int t = 0; t < 2; t++)
    #pragma unroll
    for (int i = 0; i < 3; i++){
      T0[6+3*t+i] = accV[0][i][t]; T1[6+3*t+i] = accV[1][i][t];
    }

  // ---- cross-wave K-reduction through reused ring (A=slots0-11, B=12-23) ----
  #define PUT12(base, T) { _Pragma("unroll") for (int j=0;j<12;j++) \
    *(f32x4*)(redf + ((base)+j)*320 + ln*20 + (quad<<2)) = T[j]; }
  #define ADD12(base, T) { _Pragma("unroll") for (int j=0;j<12;j++) \
    T[j] += *(const f32x4*)(redf + ((base)+j)*320 + ln*20 + (quad<<2)); }

  __syncthreads();                               // all waves drained own DMA (vmcnt 0)
  if (wv==1) PUT12(0, T0);  if (wv==2) PUT12(12, T1);
  __syncthreads();
  if (wv==0) ADD12(0, T0);  if (wv==3) ADD12(12, T1);
  __syncthreads();
  if (wv==2) PUT12(0, T0);  if (wv==1) PUT12(12, T1);
  __syncthreads();
  if (wv==0) ADD12(0, T0);  if (wv==3) ADD12(12, T1);
  __syncthreads();
  if (wv==3) PUT12(0, T0);  if (wv==0) PUT12(12, T1);
  __syncthreads();
  if (wv==0) ADD12(0, T0);  if (wv==3) ADD12(12, T1);
  // w0 now owns final sub0 tiles in T0; w3 owns final sub1 in T1.

  if (wv == 1 || wv == 2) return;
  const int s = (wv == 0) ? 0 : 1;
  f32x4* P = (wv == 0) ? T0 : T1;

  // ---- FC chain (owner wave, wave-private h buffer aliased on x1 region) ----
  f32x4 accF[4] = {z4,z4,z4,z4};
  {
    const float* fwp = few + (size_t)(ebase + s*16 + ln)*128;
    const short8* B = (const short8*)(wsb + FC1_OFF);
    #pragma unroll
    for (int c = 0; c < 4; c++){
      float4 fa  = *(const float4*)(fwp + c*32 + q8);
      float4 fbv = *(const float4*)(fwp + c*32 + q8 + 4);
      U8 a;
      a.u[0]=f2b2(fa.x,fa.y);   a.u[1]=f2b2(fa.z,fa.w);
      a.u[2]=f2b2(fbv.x,fbv.y); a.u[3]=f2b2(fbv.z,fbv.w);
      #pragma unroll
      for (int t = 0; t < 4; t++) accF[t] = mfma16(a.v, B[(c*4+t)*64 + lane], accF[t]);
    }
  }
  #pragma unroll
  for (int t = 0; t < 4; t++){
    float bb = fb1[(t<<4)+ln];
    #pragma unroll
    for (int r = 0; r < 4; r++)
      HB(wv, (quad<<2)+r, (t<<4)+ln) = f2b(silu_f(accF[t][r] + bb));
  }
  f32x4 acc2[4] = {z4,z4,z4,z4};
  {
    const short8* B = (const short8*)(wsb + FC2_OFF);
    #pragma unroll
    for (int c = 0; c < 2; c++){
      uint4 hq = *(const uint4*)&HB(wv, ln, c*32 + q8);
      U8 a; a.u[0]=hq.x; a.u[1]=hq.y; a.u[2]=hq.z; a.u[3]=hq.w;
      #pragma unroll
      for (int t = 0; t < 4; t++) acc2[t] = mfma16(a.v, B[(c*4+t)*64 + lane], acc2[t]);
    }
  }
  #pragma unroll
  for (int t = 0; t < 4; t++){
    float bb = fb2[(t<<4)+ln];
    #pragma unroll
    for (int r = 0; r < 4; r++)
      HB(wv, (quad<<2)+r, (t<<4)+ln) = f2b(silu_f(acc2[t][r] + bb));
  }
  f32x4 acc3[6] = {z4,z4,z4,z4,z4,z4};
  {
    const short8* B = (const short8*)(wsb + FC3_OFF);
    #pragma unroll
    for (int c = 0; c < 2; c++){
      uint4 hq = *(const uint4*)&HB(wv, ln, c*32 + q8);
      U8 a; a.u[0]=hq.x; a.u[1]=hq.y; a.u[2]=hq.z; a.u[3]=hq.w;
      #pragma unroll
      for (int t = 0; t < 6; t++) acc3[t] = mfma16(a.v, B[(c*6+t)*64 + lane], acc3[t]);
    }
  }

  // ---- epilogue (C-layout row = quad*4+r; 625*32 = 20000, no guards) ----
  #pragma unroll
  for (int r = 0; r < 4; r++){
    int eg = ebase + s*16 + (quad<<2) + r;
    float* op = out + (size_t)eg*160;
    #pragma unroll
    for (int t = 0; t < 4; t++)
      op[(t<<4)+ln] = silu_f(P[t][r]) * (acc3[t][r] + fb3[(t<<4)+ln]);
    #pragma unroll
    for (int tp = 0; tp < 2; tp++){
      int wc = (tp<<4) + ln;
      float f = sigm_f(P[4+tp][r]) * (acc3[4+tp][r] + fb3[64+wc]);
      op[64 + wc*3 + 0] = P[6+3*tp+0][r] * f;
      op[64 + wc*3 + 1] = P[6+3*tp+1][r] * f;
      op[64 + wc*3 + 2] = P[6+3*tp+2][r] * f;
    }
  }
}

extern "C" void kernel_launch(void* const* d_in, const int* in_sizes, int n_in,
                              void* d_out, int out_size, void* d_ws, size_t ws_size,
                              hipStream_t stream) {
  (void)in_sizes; (void)n_in; (void)out_size; (void)ws_size;
  unsigned short* wsb = (unsigned short*)d_ws;

  prep_weights<<<(WS_USH/8 + 255)/256, 256, 0, stream>>>(
      (const float*)d_in[3], (const float*)d_in[5],     // ss_s, ss_g
      (const float*)d_in[4], (const float*)d_in[6],     // vv_s, vv_g
      (const float*)d_in[7], (const float*)d_in[8],     // sv, vs
      (const float*)d_in[9], (const float*)d_in[11], (const float*)d_in[13],
      wsb);

  equiconv_main<<<E_TOT/32, 256, 0, stream>>>(
      (const float*)d_in[0], (const float*)d_in[1], (const float*)d_in[2],
      (const float*)d_in[10], (const float*)d_in[12], (const float*)d_in[14],
      (const unsigned short*)wsb, (float*)d_out);
}

// Round 8
// 182.354 us; speedup vs baseline: 1.0485x; 1.0485x over previous
//
#include <hip/hip_runtime.h>

// EquiConv fused MFMA kernel for MI355X (gfx950) — round 11 (2nd resubmit;
// R6/R7 benches both died with "MI355X container failed twice" = infra-level,
// no compile/run diagnostics. Source audited for container-killers: all
// workspace/LDS accesses in bounds, no unbounded loops, no deadlockable waits.
// Submitting identical source to finally get the measurement.)
// R10 post-mortem: launch_bounds(256,3) forced acc spills (WRITE 12.5->75MB,
// FETCH 24->50MB) -> 96-f32 acc/wave caps us at 2 waves/SIMD permanently.
// R11 keeps 2 waves/SIMD and instead removes the two never-isolated structural
// constants: the global_load_lds DMA ring and ALL sched_barrier/s_waitcnt
// scaffolding. B-fragments now load L2->VGPR into a 2-deep statically-named
// register double-buffer (bA/bB, 48 VGPRs); the compiler places per-register
// vmcnt waits and may hoist X1 ds_reads + PACK VALU across chunk boundaries
// (previously pinned). LDS shrinks to redf+x1 (41KB). Arithmetic order
// identical to R10 -> absmax canary 0.03125. prep_weights unchanged (R7).

#define E_TOT 20000

typedef __attribute__((ext_vector_type(8))) short short8;
typedef __attribute__((ext_vector_type(4))) float f32x4;
typedef __attribute__((ext_vector_type(2))) __bf16 bf16x2;

#define FRAG_USH 512
#define CH_USH   3072          // 6 frags = 6KB (stream layout unit)
#define N_CH     52
#define STRIDE_W 159744        // 312 frags * 512 ushort per wave stream
#define FC1_OFF  638976        // 4*STRIDE_W
#define FC2_OFF  647168
#define FC3_OFF  651264
#define WS_USH   657408        // 1.28 MB of d_ws

// LDS pool carve (bytes): redf 30720 | x1s 4224 | x1v 6272 ; hb aliases x1
#define X1S_OFF  30720
#define X1V_OFF  34944
#define POOL_B   41216

__device__ __forceinline__ unsigned short f2b(float f){
  return __builtin_bit_cast(unsigned short, (__bf16)f);
}
__device__ __forceinline__ unsigned f2b2(float lo, float hi){
  bf16x2 t; t[0] = (__bf16)lo; t[1] = (__bf16)hi;
  return __builtin_bit_cast(unsigned, t);
}
__device__ __forceinline__ float b2f(unsigned short h){
  return __uint_as_float(((unsigned)h) << 16);
}
__device__ __forceinline__ float ulo(unsigned u){ return __uint_as_float(u << 16); }
__device__ __forceinline__ float uhi(unsigned u){ return __uint_as_float(u & 0xFFFF0000u); }
__device__ __forceinline__ f32x4 mfma16(short8 a, short8 b, f32x4 c){
  return __builtin_amdgcn_mfma_f32_16x16x32_bf16(a, b, c, 0, 0, 0);
}
union U8 { short8 v; unsigned u[4]; };
__device__ __forceinline__ float silu_f(float x){ return x/(1.f+__expf(-x)); }
__device__ __forceinline__ float sigm_f(float x){ return 1.f/(1.f+__expf(-x)); }

// PACK8P: a = bf16(s * unpack(xp[0..3])), pair order (lo,hi) == (x[2q],x[2q+1])
#define PACK8P(a, s, xp) { \
  a.u[0]=f2b2((s)*ulo((xp)[0]),(s)*uhi((xp)[0])); \
  a.u[1]=f2b2((s)*ulo((xp)[1]),(s)*uhi((xp)[1])); \
  a.u[2]=f2b2((s)*ulo((xp)[2]),(s)*uhi((xp)[2])); \
  a.u[3]=f2b2((s)*ulo((xp)[3]),(s)*uhi((xp)[3])); }

// dest position of (k_local, n16) inside a 512-ushort fragment
__device__ __forceinline__ int fpos(int kl, int n16){
  return (kl>>3)*128 + n16*8 + (kl&7);
}

// ---------------- prep: dest-linear gather into per-wave streams ----------------
__global__ void prep_weights(const float* __restrict__ ss_s, const float* __restrict__ ss_g,
                             const float* __restrict__ vv_s, const float* __restrict__ vv_g,
                             const float* __restrict__ sv,   const float* __restrict__ vs,
                             const float* __restrict__ w1,   const float* __restrict__ w2,
                             const float* __restrict__ w3,   unsigned short* __restrict__ wsb)
{
  int g = blockIdx.x * 256 + threadIdx.x;
  if (g >= WS_USH/8) return;
  const int dest = g << 3;
  const float A_SC  = 0.013975424859373686f;                     // 1/sqrt(S*S+V*V)
  const float A_VV  = (float)(0.013975424859373686 * 0.5773502691896258);
  const float A_VEC = 0.015625f;                                 // 1/sqrt(2*S*V)

  const float* src = nullptr;
  int stride = 0;
  float scale = 1.f;

  if (dest < FC1_OFF) {                      // 4 per-wave streams
    int wave = dest / STRIDE_W;
    int off  = dest - wave*STRIDE_W;
    int c    = off / CH_USH;
    int rem  = off - c*CH_USH;
    int t    = rem >> 9;                     // fragment 0..5
    int p    = rem & 511;
    int kl   = (p >> 7) << 3;                // base kl; +j inside group
    int n16  = (p >> 3) & 15;
    if (c < 32) {                            // SS: ss_s (t0..3) + ss_g (t4,5)
      int u = (wave<<4) + (c>>1);
      int v = ((c&1)<<5) + kl;
      if (t < 4) { src = ss_s + (u<<12)+(v<<6)+((t<<4)+n16);     stride = 64; }
      else       { src = ss_g + (u<<11)+(v<<5)+(((t-4)<<4)+n16); stride = 32; }
      scale = A_SC;
    } else if (c < 40) {                     // VV: vv_s (t0..3) + vv_g (t4,5)
      int u = (wave<<3) + (c-32);
      int v = kl;
      if (t < 4) { src = vv_s + (u<<11)+(v<<6)+((t<<4)+n16);     stride = 64; }
      else       { src = vv_g + (u<<10)+(v<<5)+(((t-4)<<4)+n16); stride = 32; }
      scale = A_VV;
    } else if (c < 46) {                     // SV: chunks 40..45, ul = ch*3 + t/2
      int ul = (c-40)*3 + (t>>1);
      if (ul < 16) {
        int u = (wave<<4) + ul;
        src = sv + (u<<10)+(kl<<5)+(((t&1)<<4)+n16);
        stride = 32; scale = A_VEC;
      }                                      // else: gap frag (c=45,t>=2) -> 0
    } else {                                 // VS: chunks 46..51
      int cc = c - 46;
      int vh = cc/3, ch3 = cc - vh*3;
      int fseq = ch3*6 + t;
      if (fseq < 16) {
        int u = (wave<<3) + (fseq>>1);
        int v = (vh<<5) + kl;
        src = vs + (u<<11)+(v<<5)+(((fseq&1)<<4)+n16);
        stride = 32; scale = A_VEC;
      }                                      // else: gap frag (ch3=2,t>=4) -> 0
    }
  } else if (dest < FC2_OFF) {               // fc1 [128][64]
    int off = dest - FC1_OFF;
    int fi = off >> 9, p = off & 511;
    int kl = (p>>7)<<3, n16 = (p>>3)&15;
    int k = ((fi>>2)<<5) + kl, n = ((fi&3)<<4) + n16;
    src = w1 + (k<<6) + n; stride = 64;
  } else if (dest < FC3_OFF) {               // fc2 [64][64]
    int off = dest - FC2_OFF;
    int fi = off >> 9, p = off & 511;
    int kl = (p>>7)<<3, n16 = (p>>3)&15;
    int k = ((fi>>2)<<5) + kl, n = ((fi&3)<<4) + n16;
    src = w2 + (k<<6) + n; stride = 64;
  } else {                                   // fc3 [64][96]
    int off = dest - FC3_OFF;
    int fi = off >> 9, p = off & 511;
    int kl = (p>>7)<<3, n16 = (p>>3)&15;
    int koff = fi/6, nhi = fi - koff*6;
    int k = (koff<<5) + kl, n = (nhi<<4) + n16;
    src = w3 + k*96 + n; stride = 96;
  }

  U8 a;
  if (src) {
    float v0 = scale * src[0*stride], v1 = scale * src[1*stride];
    float v2 = scale * src[2*stride], v3 = scale * src[3*stride];
    float v4 = scale * src[4*stride], v5 = scale * src[5*stride];
    float v6 = scale * src[6*stride], v7 = scale * src[7*stride];
    a.u[0] = f2b2(v0, v1); a.u[1] = f2b2(v2, v3);
    a.u[2] = f2b2(v4, v5); a.u[3] = f2b2(v6, v7);
  } else {
    a.u[0] = 0; a.u[1] = 0; a.u[2] = 0; a.u[3] = 0;
  }
  *(short8*)(wsb + dest) = a.v;
}

// ---------------- main fused kernel ----------------
__global__ __launch_bounds__(256, 2)
void equiconv_main(const float* __restrict__ fea1,
                   const float* __restrict__ fea2,
                   const float* __restrict__ few,
                   const float* __restrict__ fb1,
                   const float* __restrict__ fb2,
                   const float* __restrict__ fb3,
                   const unsigned short* __restrict__ wsb,
                   float* __restrict__ out)
{
  __shared__ __align__(16) unsigned char pool[POOL_B];
  float*          redf = (float*)pool;                          // [0, 30720)
  unsigned short* x1s_ = (unsigned short*)(pool + X1S_OFF);     // 32*66*2
  unsigned short* x1v_ = (unsigned short*)(pool + X1V_OFF);     // 32*98*2
  unsigned short* hb_  = (unsigned short*)(pool + X1S_OFF);     // alias x1 (dead post-K)

  #define X1S(r, cc) x1s_[(r)*66 + (cc)]
  #define X1V(r, cc) x1v_[(r)*98 + (cc)]
  #define HB(w, r, cc) hb_[(((w)<<4) + (r))*72 + (cc)]

  const int tid  = threadIdx.x;
  const int lane = tid & 63, wv = tid >> 6;
  const int ln   = lane & 15, quad = lane >> 4, q8 = quad << 3;
  const int ebase = blockIdx.x << 5;          // 625 * 32 == 20000 exactly

  // ---- stage x1 (32 edges) into LDS as bf16 ----
  for (int it = tid; it < 1280; it += 256){
    int row = it / 40, seg = it - row*40;
    float4 v1 = *(const float4*)(fea1 + (size_t)(ebase + row)*160 + seg*4);
    const float* p1 = (const float*)&v1;
    int c0 = seg*4;
    #pragma unroll
    for (int jj = 0; jj < 4; jj++){
      int col = c0 + jj;
      if (col < 64) X1S(row, col) = f2b(p1[jj]);
      else          X1V(row, col-64) = f2b(p1[jj]);
    }
  }
  __syncthreads();

  // ---- hoist per-lane x2 fragments, packed as bf16 pairs (40 VGPRs) ----
  unsigned xep[2][4], xop[2][4], y0p[2][4], y1p[2][4], y2p[2][4];
  #pragma unroll
  for (int s = 0; s < 2; s++){
    const float* p = fea2 + (size_t)(ebase + s*16 + ln)*160;
    float4 a0 = *(const float4*)(p + q8);
    float4 a1 = *(const float4*)(p + q8 + 4);
    float4 b0 = *(const float4*)(p + 32 + q8);
    float4 b1 = *(const float4*)(p + 36 + q8);
    xep[s][0]=f2b2(a0.x,a0.y); xep[s][1]=f2b2(a0.z,a0.w);
    xep[s][2]=f2b2(a1.x,a1.y); xep[s][3]=f2b2(a1.z,a1.w);
    xop[s][0]=f2b2(b0.x,b0.y); xop[s][1]=f2b2(b0.z,b0.w);
    xop[s][2]=f2b2(b1.x,b1.y); xop[s][3]=f2b2(b1.z,b1.w);
    const float* py = p + 64 + q8*3;
    float yb[24];
    #pragma unroll
    for (int t = 0; t < 12; t++){
      float2 f2v = *(const float2*)(py + 2*t);
      yb[2*t] = f2v.x; yb[2*t+1] = f2v.y;
    }
    #pragma unroll
    for (int q = 0; q < 4; q++){
      y0p[s][q] = f2b2(yb[6*q+0], yb[6*q+3]);
      y1p[s][q] = f2b2(yb[6*q+1], yb[6*q+4]);
      y2p[s][q] = f2b2(yb[6*q+2], yb[6*q+5]);
    }
  }

  // ---- register double-buffered B-fragment stream (no LDS, no fences) ----
  const unsigned short* gstream = wsb + (size_t)wv*STRIDE_W + lane*8;
  auto LD = [&](int c, short8* buf){
    const unsigned short* g = gstream + c*CH_USH;
    #pragma unroll
    for (int t = 0; t < 6; t++) buf[t] = *(const short8*)(g + t*FRAG_USH);
  };

  const int r0 = ln, r1 = 16 + ln;            // x1 rows for sub0/sub1
  const f32x4 z4 = {0.f,0.f,0.f,0.f};
  f32x4 accS[2][6] = {{z4,z4,z4,z4,z4,z4},{z4,z4,z4,z4,z4,z4}};
  f32x4 accV[2][3][2] = {{{z4,z4},{z4,z4},{z4,z4}},{{z4,z4},{z4,z4},{z4,z4}}};

  short8 bA[6], bB[6];
  LD(0, bA);

  // ===== SS: chunks 0..31; c = 2*u16 + half (even->bA, odd->bB) =====
  #pragma unroll 1
  for (int cc = 0; cc < 16; cc++){
    int u = (wv<<4) + cc;
    float s0 = b2f(X1S(r0, u));
    float s1 = b2f(X1S(r1, u));
    {                                        // chunk 2cc (even, xe) from bA
      LD(2*cc+1, bB);
      U8 a0, a1;
      PACK8P(a0, s0, xep[0]); PACK8P(a1, s1, xep[1]);
      #pragma unroll
      for (int t = 0; t < 6; t++){
        accS[0][t] = mfma16(a0.v, bA[t], accS[0][t]);
        accS[1][t] = mfma16(a1.v, bA[t], accS[1][t]);
      }
    }
    {                                        // chunk 2cc+1 (odd, xo) from bB
      LD(2*cc+2, bA);                        // cc=15 -> chunk 32 (VV) valid
      U8 a0, a1;
      PACK8P(a0, s0, xop[0]); PACK8P(a1, s1, xop[1]);
      #pragma unroll
      for (int t = 0; t < 6; t++){
        accS[0][t] = mfma16(a0.v, bB[t], accS[0][t]);
        accS[1][t] = mfma16(a1.v, bB[t], accS[1][t]);
      }
    }
  }
  // ===== VV: chunks 32..39; one u per chunk =====
  #define VVA(uV, s, aa) { \
    int rr = (s) ? r1 : r0; \
    float c0 = b2f(X1V(rr, (uV)*3+0)); \
    float c1 = b2f(X1V(rr, (uV)*3+1)); \
    float c2 = b2f(X1V(rr, (uV)*3+2)); \
    _Pragma("unroll") \
    for (int q = 0; q < 4; q++){ \
      float lo = c0*ulo(y0p[s][q]) + c1*ulo(y1p[s][q]) + c2*ulo(y2p[s][q]); \
      float hi = c0*uhi(y0p[s][q]) + c1*uhi(y1p[s][q]) + c2*uhi(y2p[s][q]); \
      aa.u[q] = f2b2(lo, hi); \
    } }
  #pragma unroll 1
  for (int k8 = 0; k8 < 8; k8 += 2){
    {                                        // chunk 32+k8 from bA
      LD(33+k8, bB);
      int u = (wv<<3) + k8;
      U8 a0, a1; VVA(u, 0, a0); VVA(u, 1, a1);
      #pragma unroll
      for (int t = 0; t < 6; t++){
        accS[0][t] = mfma16(a0.v, bA[t], accS[0][t]);
        accS[1][t] = mfma16(a1.v, bA[t], accS[1][t]);
      }
    }
    {                                        // chunk 33+k8 from bB
      LD(34+k8, bA);                         // k8=6 -> chunk 40 (SV) valid
      int u = (wv<<3) + k8 + 1;
      U8 a0, a1; VVA(u, 0, a0); VVA(u, 1, a1);
      #pragma unroll
      for (int t = 0; t < 6; t++){
        accS[0][t] = mfma16(a0.v, bB[t], accS[0][t]);
        accS[1][t] = mfma16(a1.v, bB[t], accS[1][t]);
      }
    }
  }
  // ===== SV: chunks 40..45; 3 u per chunk, 2 frags each =====
  #define SVBODY(chv, buf) { \
    _Pragma("unroll") \
    for (int uu = 0; uu < 3; uu++){ \
      int ui = (chv)*3 + uu; \
      if (ui < 16){ \
        int u = (wv<<4) + ui; \
        float s0 = b2f(X1S(r0, u)); \
        float s1 = b2f(X1S(r1, u)); \
        U8 a[2][3]; \
        PACK8P(a[0][0], s0, y0p[0]); PACK8P(a[0][1], s0, y1p[0]); PACK8P(a[0][2], s0, y2p[0]); \
        PACK8P(a[1][0], s1, y0p[1]); PACK8P(a[1][1], s1, y1p[1]); PACK8P(a[1][2], s1, y2p[1]); \
        _Pragma("unroll") \
        for (int t = 0; t < 2; t++){ \
          short8 b8 = buf[uu*2 + t]; \
          _Pragma("unroll") \
          for (int s = 0; s < 2; s++) \
            _Pragma("unroll") \
            for (int i = 0; i < 3; i++) \
              accV[s][i][t] = mfma16(a[s][i].v, b8, accV[s][i][t]); \
        } \
      } \
    } }
  #pragma unroll 1
  for (int ch = 0; ch < 6; ch += 2){
    { LD(41+ch, bB); SVBODY(ch, bA); }
    { LD(42+ch, bA); SVBODY(ch+1, bB); }     // ch=4 -> chunk 46 (VS) valid
  }
  // ===== VS: chunks 46..51; phase p (xe/xo), 3 u per chunk, 2 frags each =====
  #define VSBODY(pcv, buf) { \
    const int p_ = (pcv)/3, ch_ = (pcv) - p_*3; \
    _Pragma("unroll") \
    for (int uu = 0; uu < 3; uu++){ \
      int ui = ch_*3 + uu; \
      if (ui < 8){ \
        int u = (wv<<3) + ui; \
        U8 a[2][3]; \
        _Pragma("unroll") \
        for (int s = 0; s < 2; s++){ \
          int rr = s ? r1 : r0; \
          float c0 = b2f(X1V(rr, u*3+0)); \
          float c1 = b2f(X1V(rr, u*3+1)); \
          float c2 = b2f(X1V(rr, u*3+2)); \
          const unsigned* xx = p_ ? xop[s] : xep[s]; \
          PACK8P(a[s][0], c0, xx); PACK8P(a[s][1], c1, xx); PACK8P(a[s][2], c2, xx); \
        } \
        _Pragma("unroll") \
        for (int t = 0; t < 2; t++){ \
          short8 b8 = buf[uu*2 + t]; \
          _Pragma("unroll") \
          for (int s = 0; s < 2; s++) \
            _Pragma("unroll") \
            for (int i = 0; i < 3; i++) \
              accV[s][i][t] = mfma16(a[s][i].v, b8, accV[s][i][t]); \
        } \
      } \
    } }
  { LD(47, bB); VSBODY(0, bA); }
  { LD(48, bA); VSBODY(1, bB); }
  { LD(49, bB); VSBODY(2, bA); }
  { LD(50, bA); VSBODY(3, bB); }
  { LD(51, bB); VSBODY(4, bA); }
  { VSBODY(5, bB); }

  // ---- gather partials: T0 = sub0's 12 tiles, T1 = sub1's ----
  f32x4 T0[12], T1[12];
  #pragma unroll
  for (int t = 0; t < 6; t++){ T0[t] = accS[0][t]; T1[t] = accS[1][t]; }
  #pragma unroll
  for (int t = 0; t < 2; t++)
    #pragma unroll
    for (int i = 0; i < 3; i++){
      T0[6+3*t+i] = accV[0][i][t]; T1[6+3*t+i] = accV[1][i][t];
    }

  // ---- cross-wave K-reduction through redf (A=slots0-11, B=12-23) ----
  #define PUT12(base, T) { _Pragma("unroll") for (int j=0;j<12;j++) \
    *(f32x4*)(redf + ((base)+j)*320 + ln*20 + (quad<<2)) = T[j]; }
  #define ADD12(base, T) { _Pragma("unroll") for (int j=0;j<12;j++) \
    T[j] += *(const f32x4*)(redf + ((base)+j)*320 + ln*20 + (quad<<2)); }

  __syncthreads();
  if (wv==1) PUT12(0, T0);  if (wv==2) PUT12(12, T1);
  __syncthreads();
  if (wv==0) ADD12(0, T0);  if (wv==3) ADD12(12, T1);
  __syncthreads();
  if (wv==2) PUT12(0, T0);  if (wv==1) PUT12(12, T1);
  __syncthreads();
  if (wv==0) ADD12(0, T0);  if (wv==3) ADD12(12, T1);
  __syncthreads();
  if (wv==3) PUT12(0, T0);  if (wv==0) PUT12(12, T1);
  __syncthreads();
  if (wv==0) ADD12(0, T0);  if (wv==3) ADD12(12, T1);
  // w0 now owns final sub0 tiles in T0; w3 owns final sub1 in T1.

  if (wv == 1 || wv == 2) return;
  const int s = (wv == 0) ? 0 : 1;
  f32x4* P = (wv == 0) ? T0 : T1;

  // ---- FC chain (owner wave, wave-private h buffer aliased on x1 region) ----
  f32x4 accF[4] = {z4,z4,z4,z4};
  {
    const float* fwp = few + (size_t)(ebase + s*16 + ln)*128;
    const short8* B = (const short8*)(wsb + FC1_OFF);
    #pragma unroll
    for (int c = 0; c < 4; c++){
      float4 fa  = *(const float4*)(fwp + c*32 + q8);
      float4 fbv = *(const float4*)(fwp + c*32 + q8 + 4);
      U8 a;
      a.u[0]=f2b2(fa.x,fa.y);   a.u[1]=f2b2(fa.z,fa.w);
      a.u[2]=f2b2(fbv.x,fbv.y); a.u[3]=f2b2(fbv.z,fbv.w);
      #pragma unroll
      for (int t = 0; t < 4; t++) accF[t] = mfma16(a.v, B[(c*4+t)*64 + lane], accF[t]);
    }
  }
  #pragma unroll
  for (int t = 0; t < 4; t++){
    float bb = fb1[(t<<4)+ln];
    #pragma unroll
    for (int r = 0; r < 4; r++)
      HB(wv, (quad<<2)+r, (t<<4)+ln) = f2b(silu_f(accF[t][r] + bb));
  }
  f32x4 acc2[4] = {z4,z4,z4,z4};
  {
    const short8* B = (const short8*)(wsb + FC2_OFF);
    #pragma unroll
    for (int c = 0; c < 2; c++){
      uint4 hq = *(const uint4*)&HB(wv, ln, c*32 + q8);
      U8 a; a.u[0]=hq.x; a.u[1]=hq.y; a.u[2]=hq.z; a.u[3]=hq.w;
      #pragma unroll
      for (int t = 0; t < 4; t++) acc2[t] = mfma16(a.v, B[(c*4+t)*64 + lane], acc2[t]);
    }
  }
  #pragma unroll
  for (int t = 0; t < 4; t++){
    float bb = fb2[(t<<4)+ln];
    #pragma unroll
    for (int r = 0; r < 4; r++)
      HB(wv, (quad<<2)+r, (t<<4)+ln) = f2b(silu_f(acc2[t][r] + bb));
  }
  f32x4 acc3[6] = {z4,z4,z4,z4,z4,z4};
  {
    const short8* B = (const short8*)(wsb + FC3_OFF);
    #pragma unroll
    for (int c = 0; c < 2; c++){
      uint4 hq = *(const uint4*)&HB(wv, ln, c*32 + q8);
      U8 a; a.u[0]=hq.x; a.u[1]=hq.y; a.u[2]=hq.z; a.u[3]=hq.w;
      #pragma unroll
      for (int t = 0; t < 6; t++) acc3[t] = mfma16(a.v, B[(c*6+t)*64 + lane], acc3[t]);
    }
  }

  // ---- epilogue (C-layout row = quad*4+r; 625*32 = 20000, no guards) ----
  #pragma unroll
  for (int r = 0; r < 4; r++){
    int eg = ebase + s*16 + (quad<<2) + r;
    float* op = out + (size_t)eg*160;
    #pragma unroll
    for (int t = 0; t < 4; t++)
      op[(t<<4)+ln] = silu_f(P[t][r]) * (acc3[t][r] + fb3[(t<<4)+ln]);
    #pragma unroll
    for (int tp = 0; tp < 2; tp++){
      int wc = (tp<<4) + ln;
      float f = sigm_f(P[4+tp][r]) * (acc3[4+tp][r] + fb3[64+wc]);
      op[64 + wc*3 + 0] = P[6+3*tp+0][r] * f;
      op[64 + wc*3 + 1] = P[6+3*tp+1][r] * f;
      op[64 + wc*3 + 2] = P[6+3*tp+2][r] * f;
    }
  }
}

extern "C" void kernel_launch(void* const* d_in, const int* in_sizes, int n_in,
                              void* d_out, int out_size, void* d_ws, size_t ws_size,
                              hipStream_t stream) {
  (void)in_sizes; (void)n_in; (void)out_size; (void)ws_size;
  unsigned short* wsb = (unsigned short*)d_ws;

  prep_weights<<<(WS_USH/8 + 255)/256, 256, 0, stream>>>(
      (const float*)d_in[3], (const float*)d_in[5],     // ss_s, ss_g
      (const float*)d_in[4], (const float*)d_in[6],     // vv_s, vv_g
      (const float*)d_in[7], (const float*)d_in[8],     // sv, vs
      (const float*)d_in[9], (const float*)d_in[11], (const float*)d_in[13],
      wsb);

  equiconv_main<<<E_TOT/32, 256, 0, stream>>>(
      (const float*)d_in[0], (const float*)d_in[1], (const float*)d_in[2],
      (const float*)d_in[10], (const float*)d_in[12], (const float*)d_in[14],
      (const unsigned short*)wsb, (float*)d_out);
}

// Round 9
// 172.209 us; speedup vs baseline: 1.1103x; 1.0589x over previous
//
#include <hip/hip_runtime.h>

// EquiConv fused MFMA kernel for MI355X (gfx950) — round 12.
// Elimination series complete (R7-R11): DMA-vs-reg, fences, wait granularity,
// prefetch depth 1/2/10 -> ALL flat at ~90us main; waves/CU scales linearly
// (R8). Model: T = wave-chunks x T_chunk / resident-waves; wave-chunks is
// read-optimal, waves capped by 96-f32 acc, T_chunk ~3Kcy with ~2Kcy
// depth-invariant stall. Remaining suspect: L2 channel hotspotting — all ~512
// resident blocks walk the SAME 1.28MB workspace in lockstep (128 waves per
// role on the same lines simultaneously). R12 = R11 + per-block staggered
// chunk order (SS pairs rotated by blockIdx&15, VV by &7, SV/VS by %6).
// Mappings preserved; only accumulation order over u changes (absmax may
// shift within tolerance). Everything else identical to R11.

#define E_TOT 20000

typedef __attribute__((ext_vector_type(8))) short short8;
typedef __attribute__((ext_vector_type(4))) float f32x4;
typedef __attribute__((ext_vector_type(2))) __bf16 bf16x2;

#define FRAG_USH 512
#define CH_USH   3072          // 6 frags = 6KB (stream layout unit)
#define N_CH     52
#define STRIDE_W 159744        // 312 frags * 512 ushort per wave stream
#define FC1_OFF  638976        // 4*STRIDE_W
#define FC2_OFF  647168
#define FC3_OFF  651264
#define WS_USH   657408        // 1.28 MB of d_ws

// LDS pool carve (bytes): redf 30720 | x1s 4224 | x1v 6272 ; hb aliases x1
#define X1S_OFF  30720
#define X1V_OFF  34944
#define POOL_B   41216

__device__ __forceinline__ unsigned short f2b(float f){
  return __builtin_bit_cast(unsigned short, (__bf16)f);
}
__device__ __forceinline__ unsigned f2b2(float lo, float hi){
  bf16x2 t; t[0] = (__bf16)lo; t[1] = (__bf16)hi;
  return __builtin_bit_cast(unsigned, t);
}
__device__ __forceinline__ float b2f(unsigned short h){
  return __uint_as_float(((unsigned)h) << 16);
}
__device__ __forceinline__ float ulo(unsigned u){ return __uint_as_float(u << 16); }
__device__ __forceinline__ float uhi(unsigned u){ return __uint_as_float(u & 0xFFFF0000u); }
__device__ __forceinline__ f32x4 mfma16(short8 a, short8 b, f32x4 c){
  return __builtin_amdgcn_mfma_f32_16x16x32_bf16(a, b, c, 0, 0, 0);
}
union U8 { short8 v; unsigned u[4]; };
__device__ __forceinline__ float silu_f(float x){ return x/(1.f+__expf(-x)); }
__device__ __forceinline__ float sigm_f(float x){ return 1.f/(1.f+__expf(-x)); }

// PACK8P: a = bf16(s * unpack(xp[0..3])), pair order (lo,hi) == (x[2q],x[2q+1])
#define PACK8P(a, s, xp) { \
  a.u[0]=f2b2((s)*ulo((xp)[0]),(s)*uhi((xp)[0])); \
  a.u[1]=f2b2((s)*ulo((xp)[1]),(s)*uhi((xp)[1])); \
  a.u[2]=f2b2((s)*ulo((xp)[2]),(s)*uhi((xp)[2])); \
  a.u[3]=f2b2((s)*ulo((xp)[3]),(s)*uhi((xp)[3])); }

// dest position of (k_local, n16) inside a 512-ushort fragment
__device__ __forceinline__ int fpos(int kl, int n16){
  return (kl>>3)*128 + n16*8 + (kl&7);
}

// ---------------- prep: dest-linear gather into per-wave streams ----------------
__global__ void prep_weights(const float* __restrict__ ss_s, const float* __restrict__ ss_g,
                             const float* __restrict__ vv_s, const float* __restrict__ vv_g,
                             const float* __restrict__ sv,   const float* __restrict__ vs,
                             const float* __restrict__ w1,   const float* __restrict__ w2,
                             const float* __restrict__ w3,   unsigned short* __restrict__ wsb)
{
  int g = blockIdx.x * 256 + threadIdx.x;
  if (g >= WS_USH/8) return;
  const int dest = g << 3;
  const float A_SC  = 0.013975424859373686f;                     // 1/sqrt(S*S+V*V)
  const float A_VV  = (float)(0.013975424859373686 * 0.5773502691896258);
  const float A_VEC = 0.015625f;                                 // 1/sqrt(2*S*V)

  const float* src = nullptr;
  int stride = 0;
  float scale = 1.f;

  if (dest < FC1_OFF) {                      // 4 per-wave streams
    int wave = dest / STRIDE_W;
    int off  = dest - wave*STRIDE_W;
    int c    = off / CH_USH;
    int rem  = off - c*CH_USH;
    int t    = rem >> 9;                     // fragment 0..5
    int p    = rem & 511;
    int kl   = (p >> 7) << 3;                // base kl; +j inside group
    int n16  = (p >> 3) & 15;
    if (c < 32) {                            // SS: ss_s (t0..3) + ss_g (t4,5)
      int u = (wave<<4) + (c>>1);
      int v = ((c&1)<<5) + kl;
      if (t < 4) { src = ss_s + (u<<12)+(v<<6)+((t<<4)+n16);     stride = 64; }
      else       { src = ss_g + (u<<11)+(v<<5)+(((t-4)<<4)+n16); stride = 32; }
      scale = A_SC;
    } else if (c < 40) {                     // VV: vv_s (t0..3) + vv_g (t4,5)
      int u = (wave<<3) + (c-32);
      int v = kl;
      if (t < 4) { src = vv_s + (u<<11)+(v<<6)+((t<<4)+n16);     stride = 64; }
      else       { src = vv_g + (u<<10)+(v<<5)+(((t-4)<<4)+n16); stride = 32; }
      scale = A_VV;
    } else if (c < 46) {                     // SV: chunks 40..45, ul = ch*3 + t/2
      int ul = (c-40)*3 + (t>>1);
      if (ul < 16) {
        int u = (wave<<4) + ul;
        src = sv + (u<<10)+(kl<<5)+(((t&1)<<4)+n16);
        stride = 32; scale = A_VEC;
      }                                      // else: gap frag (c=45,t>=2) -> 0
    } else {                                 // VS: chunks 46..51
      int cc = c - 46;
      int vh = cc/3, ch3 = cc - vh*3;
      int fseq = ch3*6 + t;
      if (fseq < 16) {
        int u = (wave<<3) + (fseq>>1);
        int v = (vh<<5) + kl;
        src = vs + (u<<11)+(v<<5)+(((fseq&1)<<4)+n16);
        stride = 32; scale = A_VEC;
      }                                      // else: gap frag (ch3=2,t>=4) -> 0
    }
  } else if (dest < FC2_OFF) {               // fc1 [128][64]
    int off = dest - FC1_OFF;
    int fi = off >> 9, p = off & 511;
    int kl = (p>>7)<<3, n16 = (p>>3)&15;
    int k = ((fi>>2)<<5) + kl, n = ((fi&3)<<4) + n16;
    src = w1 + (k<<6) + n; stride = 64;
  } else if (dest < FC3_OFF) {               // fc2 [64][64]
    int off = dest - FC2_OFF;
    int fi = off >> 9, p = off & 511;
    int kl = (p>>7)<<3, n16 = (p>>3)&15;
    int k = ((fi>>2)<<5) + kl, n = ((fi&3)<<4) + n16;
    src = w2 + (k<<6) + n; stride = 64;
  } else {                                   // fc3 [64][96]
    int off = dest - FC3_OFF;
    int fi = off >> 9, p = off & 511;
    int kl = (p>>7)<<3, n16 = (p>>3)&15;
    int koff = fi/6, nhi = fi - koff*6;
    int k = (koff<<5) + kl, n = (nhi<<4) + n16;
    src = w3 + k*96 + n; stride = 96;
  }

  U8 a;
  if (src) {
    float v0 = scale * src[0*stride], v1 = scale * src[1*stride];
    float v2 = scale * src[2*stride], v3 = scale * src[3*stride];
    float v4 = scale * src[4*stride], v5 = scale * src[5*stride];
    float v6 = scale * src[6*stride], v7 = scale * src[7*stride];
    a.u[0] = f2b2(v0, v1); a.u[1] = f2b2(v2, v3);
    a.u[2] = f2b2(v4, v5); a.u[3] = f2b2(v6, v7);
  } else {
    a.u[0] = 0; a.u[1] = 0; a.u[2] = 0; a.u[3] = 0;
  }
  *(short8*)(wsb + dest) = a.v;
}

// ---------------- main fused kernel ----------------
__global__ __launch_bounds__(256, 2)
void equiconv_main(const float* __restrict__ fea1,
                   const float* __restrict__ fea2,
                   const float* __restrict__ few,
                   const float* __restrict__ fb1,
                   const float* __restrict__ fb2,
                   const float* __restrict__ fb3,
                   const unsigned short* __restrict__ wsb,
                   float* __restrict__ out)
{
  __shared__ __align__(16) unsigned char pool[POOL_B];
  float*          redf = (float*)pool;                          // [0, 30720)
  unsigned short* x1s_ = (unsigned short*)(pool + X1S_OFF);     // 32*66*2
  unsigned short* x1v_ = (unsigned short*)(pool + X1V_OFF);     // 32*98*2
  unsigned short* hb_  = (unsigned short*)(pool + X1S_OFF);     // alias x1 (dead post-K)

  #define X1S(r, cc) x1s_[(r)*66 + (cc)]
  #define X1V(r, cc) x1v_[(r)*98 + (cc)]
  #define HB(w, r, cc) hb_[(((w)<<4) + (r))*72 + (cc)]

  const int tid  = threadIdx.x;
  const int lane = tid & 63, wv = tid >> 6;
  const int ln   = lane & 15, quad = lane >> 4, q8 = quad << 3;
  const int ebase = blockIdx.x << 5;          // 625 * 32 == 20000 exactly

  // per-block chunk-order stagger (L2 channel spread); block-uniform
  const int off16 = blockIdx.x & 15;
  const int off8  = blockIdx.x & 7;
  const int off6  = blockIdx.x % 6;

  // ---- stage x1 (32 edges) into LDS as bf16 ----
  for (int it = tid; it < 1280; it += 256){
    int row = it / 40, seg = it - row*40;
    float4 v1 = *(const float4*)(fea1 + (size_t)(ebase + row)*160 + seg*4);
    const float* p1 = (const float*)&v1;
    int c0 = seg*4;
    #pragma unroll
    for (int jj = 0; jj < 4; jj++){
      int col = c0 + jj;
      if (col < 64) X1S(row, col) = f2b(p1[jj]);
      else          X1V(row, col-64) = f2b(p1[jj]);
    }
  }
  __syncthreads();

  // ---- hoist per-lane x2 fragments, packed as bf16 pairs (40 VGPRs) ----
  unsigned xep[2][4], xop[2][4], y0p[2][4], y1p[2][4], y2p[2][4];
  #pragma unroll
  for (int s = 0; s < 2; s++){
    const float* p = fea2 + (size_t)(ebase + s*16 + ln)*160;
    float4 a0 = *(const float4*)(p + q8);
    float4 a1 = *(const float4*)(p + q8 + 4);
    float4 b0 = *(const float4*)(p + 32 + q8);
    float4 b1 = *(const float4*)(p + 36 + q8);
    xep[s][0]=f2b2(a0.x,a0.y); xep[s][1]=f2b2(a0.z,a0.w);
    xep[s][2]=f2b2(a1.x,a1.y); xep[s][3]=f2b2(a1.z,a1.w);
    xop[s][0]=f2b2(b0.x,b0.y); xop[s][1]=f2b2(b0.z,b0.w);
    xop[s][2]=f2b2(b1.x,b1.y); xop[s][3]=f2b2(b1.z,b1.w);
    const float* py = p + 64 + q8*3;
    float yb[24];
    #pragma unroll
    for (int t = 0; t < 12; t++){
      float2 f2v = *(const float2*)(py + 2*t);
      yb[2*t] = f2v.x; yb[2*t+1] = f2v.y;
    }
    #pragma unroll
    for (int q = 0; q < 4; q++){
      y0p[s][q] = f2b2(yb[6*q+0], yb[6*q+3]);
      y1p[s][q] = f2b2(yb[6*q+1], yb[6*q+4]);
      y2p[s][q] = f2b2(yb[6*q+2], yb[6*q+5]);
    }
  }

  // ---- register double-buffered B-fragment stream (runtime chunk indices) ----
  const unsigned short* gstream = wsb + (size_t)wv*STRIDE_W + lane*8;
  auto LD = [&](int c, short8* buf){
    const unsigned short* g = gstream + c*CH_USH;
    #pragma unroll
    for (int t = 0; t < 6; t++) buf[t] = *(const short8*)(g + t*FRAG_USH);
  };

  const int r0 = ln, r1 = 16 + ln;            // x1 rows for sub0/sub1
  const f32x4 z4 = {0.f,0.f,0.f,0.f};
  f32x4 accS[2][6] = {{z4,z4,z4,z4,z4,z4},{z4,z4,z4,z4,z4,z4}};
  f32x4 accV[2][3][2] = {{{z4,z4},{z4,z4},{z4,z4}},{{z4,z4},{z4,z4},{z4,z4}}};

  short8 bA[6], bB[6];
  LD(2*off16, bA);                            // first visited SS pair, even chunk

  // ===== SS: pairs rotated by off16; pair p -> chunks 2p (xe), 2p+1 (xo) =====
  #pragma unroll 1
  for (int i = 0; i < 16; i++){
    int p  = (i + off16) & 15;
    int pn = (i + 1 + off16) & 15;
    int u = (wv<<4) + p;
    float s0 = b2f(X1S(r0, u));
    float s1 = b2f(X1S(r1, u));
    {                                        // even chunk 2p from bA
      LD(2*p+1, bB);
      U8 a0, a1;
      PACK8P(a0, s0, xep[0]); PACK8P(a1, s1, xep[1]);
      #pragma unroll
      for (int t = 0; t < 6; t++){
        accS[0][t] = mfma16(a0.v, bA[t], accS[0][t]);
        accS[1][t] = mfma16(a1.v, bA[t], accS[1][t]);
      }
    }
    {                                        // odd chunk 2p+1 from bB
      int nextc = (i < 15) ? 2*pn : (32 + off8);   // next pair even | first VV
      LD(nextc, bA);
      U8 a0, a1;
      PACK8P(a0, s0, xop[0]); PACK8P(a1, s1, xop[1]);
      #pragma unroll
      for (int t = 0; t < 6; t++){
        accS[0][t] = mfma16(a0.v, bB[t], accS[0][t]);
        accS[1][t] = mfma16(a1.v, bB[t], accS[1][t]);
      }
    }
  }
  // ===== VV: 8 chunks rotated by off8 =====
  #define VVA(uV, s, aa) { \
    int rr = (s) ? r1 : r0; \
    float c0 = b2f(X1V(rr, (uV)*3+0)); \
    float c1 = b2f(X1V(rr, (uV)*3+1)); \
    float c2 = b2f(X1V(rr, (uV)*3+2)); \
    _Pragma("unroll") \
    for (int q = 0; q < 4; q++){ \
      float lo = c0*ulo(y0p[s][q]) + c1*ulo(y1p[s][q]) + c2*ulo(y2p[s][q]); \
      float hi = c0*uhi(y0p[s][q]) + c1*uhi(y1p[s][q]) + c2*uhi(y2p[s][q]); \
      aa.u[q] = f2b2(lo, hi); \
    } }
  #pragma unroll 1
  for (int j = 0; j < 8; j += 2){
    int k0 = (j + off8) & 7;
    int k1 = (j + 1 + off8) & 7;
    int k2 = (j + 2 + off8) & 7;
    {                                        // chunk 32+k0 from bA
      LD(32+k1, bB);
      int u = (wv<<3) + k0;
      U8 a0, a1; VVA(u, 0, a0); VVA(u, 1, a1);
      #pragma unroll
      for (int t = 0; t < 6; t++){
        accS[0][t] = mfma16(a0.v, bA[t], accS[0][t]);
        accS[1][t] = mfma16(a1.v, bA[t], accS[1][t]);
      }
    }
    {                                        // chunk 32+k1 from bB
      int nextc = (j < 6) ? (32 + k2) : (40 + off6);   // next VV | first SV
      LD(nextc, bA);
      int u = (wv<<3) + k1;
      U8 a0, a1; VVA(u, 0, a0); VVA(u, 1, a1);
      #pragma unroll
      for (int t = 0; t < 6; t++){
        accS[0][t] = mfma16(a0.v, bB[t], accS[0][t]);
        accS[1][t] = mfma16(a1.v, bB[t], accS[1][t]);
      }
    }
  }
  // ===== SV: 6 chunks rotated by off6; body index = chunk index (runtime) =====
  #define SVBODY(chv, buf) { \
    _Pragma("unroll") \
    for (int uu = 0; uu < 3; uu++){ \
      int ui = (chv)*3 + uu; \
      if (ui < 16){ \
        int u = (wv<<4) + ui; \
        float s0 = b2f(X1S(r0, u)); \
        float s1 = b2f(X1S(r1, u)); \
        U8 a[2][3]; \
        PACK8P(a[0][0], s0, y0p[0]); PACK8P(a[0][1], s0, y1p[0]); PACK8P(a[0][2], s0, y2p[0]); \
        PACK8P(a[1][0], s1, y0p[1]); PACK8P(a[1][1], s1, y1p[1]); PACK8P(a[1][2], s1, y2p[1]); \
        _Pragma("unroll") \
        for (int t = 0; t < 2; t++){ \
          short8 b8 = buf[uu*2 + t]; \
          _Pragma("unroll") \
          for (int s = 0; s < 2; s++) \
            _Pragma("unroll") \
            for (int i2 = 0; i2 < 3; i2++) \
              accV[s][i2][t] = mfma16(a[s][i2].v, b8, accV[s][i2][t]); \
        } \
      } \
    } }
  #pragma unroll 1
  for (int j = 0; j < 6; j += 2){
    int c0i = j + off6;     if (c0i >= 6) c0i -= 6;
    int c1i = j + 1 + off6; if (c1i >= 6) c1i -= 6;
    int c2i = j + 2 + off6; if (c2i >= 6) c2i -= 6;
    { LD(40 + c1i, bB); SVBODY(c0i, bA); }
    {
      int nextc = (j < 4) ? (40 + c2i) : (46 + off6);  // next SV | first VS
      LD(nextc, bA);
      SVBODY(c1i, bB);
    }
  }
  // ===== VS: 6 chunks rotated by off6; phase p = pcv/3 (runtime) =====
  #define VSBODY(pcv, buf) { \
    const int p_ = (pcv)/3, ch_ = (pcv) - p_*3; \
    _Pragma("unroll") \
    for (int uu = 0; uu < 3; uu++){ \
      int ui = ch_*3 + uu; \
      if (ui < 8){ \
        int u = (wv<<3) + ui; \
        U8 a[2][3]; \
        _Pragma("unroll") \
        for (int s = 0; s < 2; s++){ \
          int rr = s ? r1 : r0; \
          float c0 = b2f(X1V(rr, u*3+0)); \
          float c1 = b2f(X1V(rr, u*3+1)); \
          float c2 = b2f(X1V(rr, u*3+2)); \
          const unsigned* xx = p_ ? xop[s] : xep[s]; \
          PACK8P(a[s][0], c0, xx); PACK8P(a[s][1], c1, xx); PACK8P(a[s][2], c2, xx); \
        } \
        _Pragma("unroll") \
        for (int t = 0; t < 2; t++){ \
          short8 b8 = buf[uu*2 + t]; \
          _Pragma("unroll") \
          for (int s = 0; s < 2; s++) \
            _Pragma("unroll") \
            for (int i2 = 0; i2 < 3; i2++) \
              accV[s][i2][t] = mfma16(a[s][i2].v, b8, accV[s][i2][t]); \
        } \
      } \
    } }
  #pragma unroll 1
  for (int j = 0; j < 6; j += 2){
    int c0i = j + off6;     if (c0i >= 6) c0i -= 6;
    int c1i = j + 1 + off6; if (c1i >= 6) c1i -= 6;
    int c2i = j + 2 + off6; if (c2i >= 6) c2i -= 6;
    { LD(46 + c1i, bB); VSBODY(c0i, bA); }
    {
      if (j < 4) LD(46 + c2i, bA);
      VSBODY(c1i, bB);
    }
  }

  // ---- gather partials: T0 = sub0's 12 tiles, T1 = sub1's ----
  f32x4 T0[12], T1[12];
  #pragma unroll
  for (int t = 0; t < 6; t++){ T0[t] = accS[0][t]; T1[t] = accS[1][t]; }
  #pragma unroll
  for (int t = 0; t < 2; t++)
    #pragma unroll
    for (int i = 0; i < 3; i++){
      T0[6+3*t+i] = accV[0][i][t]; T1[6+3*t+i] = accV[1][i][t];
    }

  // ---- cross-wave K-reduction through redf (A=slots0-11, B=12-23) ----
  #define PUT12(base, T) { _Pragma("unroll") for (int j=0;j<12;j++) \
    *(f32x4*)(redf + ((base)+j)*320 + ln*20 + (quad<<2)) = T[j]; }
  #define ADD12(base, T) { _Pragma("unroll") for (int j=0;j<12;j++) \
    T[j] += *(const f32x4*)(redf + ((base)+j)*320 + ln*20 + (quad<<2)); }

  __syncthreads();
  if (wv==1) PUT12(0, T0);  if (wv==2) PUT12(12, T1);
  __syncthreads();
  if (wv==0) ADD12(0, T0);  if (wv==3) ADD12(12, T1);
  __syncthreads();
  if (wv==2) PUT12(0, T0);  if (wv==1) PUT12(12, T1);
  __syncthreads();
  if (wv==0) ADD12(0, T0);  if (wv==3) ADD12(12, T1);
  __syncthreads();
  if (wv==3) PUT12(0, T0);  if (wv==0) PUT12(12, T1);
  __syncthreads();
  if (wv==0) ADD12(0, T0);  if (wv==3) ADD12(12, T1);
  // w0 now owns final sub0 tiles in T0; w3 owns final sub1 in T1.

  if (wv == 1 || wv == 2) return;
  const int s = (wv == 0) ? 0 : 1;
  f32x4* P = (wv == 0) ? T0 : T1;

  // ---- FC chain (owner wave, wave-private h buffer aliased on x1 region) ----
  f32x4 accF[4] = {z4,z4,z4,z4};
  {
    const float* fwp = few + (size_t)(ebase + s*16 + ln)*128;
    const short8* B = (const short8*)(wsb + FC1_OFF);
    #pragma unroll
    for (int c = 0; c < 4; c++){
      float4 fa  = *(const float4*)(fwp + c*32 + q8);
      float4 fbv = *(const float4*)(fwp + c*32 + q8 + 4);
      U8 a;
      a.u[0]=f2b2(fa.x,fa.y);   a.u[1]=f2b2(fa.z,fa.w);
      a.u[2]=f2b2(fbv.x,fbv.y); a.u[3]=f2b2(fbv.z,fbv.w);
      #pragma unroll
      for (int t = 0; t < 4; t++) accF[t] = mfma16(a.v, B[(c*4+t)*64 + lane], accF[t]);
    }
  }
  #pragma unroll
  for (int t = 0; t < 4; t++){
    float bb = fb1[(t<<4)+ln];
    #pragma unroll
    for (int r = 0; r < 4; r++)
      HB(wv, (quad<<2)+r, (t<<4)+ln) = f2b(silu_f(accF[t][r] + bb));
  }
  f32x4 acc2[4] = {z4,z4,z4,z4};
  {
    const short8* B = (const short8*)(wsb + FC2_OFF);
    #pragma unroll
    for (int c = 0; c < 2; c++){
      uint4 hq = *(const uint4*)&HB(wv, ln, c*32 + q8);
      U8 a; a.u[0]=hq.x; a.u[1]=hq.y; a.u[2]=hq.z; a.u[3]=hq.w;
      #pragma unroll
      for (int t = 0; t < 4; t++) acc2[t] = mfma16(a.v, B[(c*4+t)*64 + lane], acc2[t]);
    }
  }
  #pragma unroll
  for (int t = 0; t < 4; t++){
    float bb = fb2[(t<<4)+ln];
    #pragma unroll
    for (int r = 0; r < 4; r++)
      HB(wv, (quad<<2)+r, (t<<4)+ln) = f2b(silu_f(acc2[t][r] + bb));
  }
  f32x4 acc3[6] = {z4,z4,z4,z4,z4,z4};
  {
    const short8* B = (const short8*)(wsb + FC3_OFF);
    #pragma unroll
    for (int c = 0; c < 2; c++){
      uint4 hq = *(const uint4*)&HB(wv, ln, c*32 + q8);
      U8 a; a.u[0]=hq.x; a.u[1]=hq.y; a.u[2]=hq.z; a.u[3]=hq.w;
      #pragma unroll
      for (int t = 0; t < 6; t++) acc3[t] = mfma16(a.v, B[(c*6+t)*64 + lane], acc3[t]);
    }
  }

  // ---- epilogue (C-layout row = quad*4+r; 625*32 = 20000, no guards) ----
  #pragma unroll
  for (int r = 0; r < 4; r++){
    int eg = ebase + s*16 + (quad<<2) + r;
    float* op = out + (size_t)eg*160;
    #pragma unroll
    for (int t = 0; t < 4; t++)
      op[(t<<4)+ln] = silu_f(P[t][r]) * (acc3[t][r] + fb3[(t<<4)+ln]);
    #pragma unroll
    for (int tp = 0; tp < 2; tp++){
      int wc = (tp<<4) + ln;
      float f = sigm_f(P[4+tp][r]) * (acc3[4+tp][r] + fb3[64+wc]);
      op[64 + wc*3 + 0] = P[6+3*tp+0][r] * f;
      op[64 + wc*3 + 1] = P[6+3*tp+1][r] * f;
      op[64 + wc*3 + 2] = P[6+3*tp+2][r] * f;
    }
  }
}

extern "C" void kernel_launch(void* const* d_in, const int* in_sizes, int n_in,
                              void* d_out, int out_size, void* d_ws, size_t ws_size,
                              hipStream_t stream) {
  (void)in_sizes; (void)n_in; (void)out_size; (void)ws_size;
  unsigned short* wsb = (unsigned short*)d_ws;

  prep_weights<<<(WS_USH/8 + 255)/256, 256, 0, stream>>>(
      (const float*)d_in[3], (const float*)d_in[5],     // ss_s, ss_g
      (const float*)d_in[4], (const float*)d_in[6],     // vv_s, vv_g
      (const float*)d_in[7], (const float*)d_in[8],     // sv, vs
      (const float*)d_in[9], (const float*)d_in[11], (const float*)d_in[13],
      wsb);

  equiconv_main<<<E_TOT/32, 256, 0, stream>>>(
      (const float*)d_in[0], (const float*)d_in[1], (const float*)d_in[2],
      (const float*)d_in[10], (const float*)d_in[12], (const float*)d_in[14],
      (const unsigned short*)wsb, (float*)d_out);
}